// Round 16
// baseline (487.892 us; speedup 1.0000x reference)
//
#include <hip/hip_runtime.h>
#include <math.h>

typedef __attribute__((ext_vector_type(4))) float f32x4;
typedef __attribute__((ext_vector_type(2))) float f32x2;
typedef __attribute__((ext_vector_type(8))) short bf16x8;
typedef __attribute__((ext_vector_type(4))) short short4v;

#define EPSN 1e-12f
#define TN 32
#define FBASE 8192      // F region base (shorts); A = [0, 8192), F = [8192, 16384)
// F region: 32 rows x 256 shorts, XOR-swizzled (no pad). u region overlays A: stride 128.
#define SWZ(row) ((((row) >> 2) & 3) << 4)

__device__ inline short f2bf(float x) {
    union { float f; unsigned u; } v; v.f = x;
    unsigned r = v.u + 0x7fffu + ((v.u >> 16) & 1u);
    return (short)(r >> 16);
}
__device__ inline float bf2f(short s) {
    union { unsigned u; float f; } v;
    v.u = ((unsigned)(unsigned short)s) << 16;
    return v.f;
}
__device__ inline float wsum64(float v) {
#pragma unroll
    for (int m = 32; m > 0; m >>= 1) v += __shfl_xor(v, m);
    return v;
}
__device__ inline float wsum16(float v) {
    v += __shfl_xor(v, 1);
    v += __shfl_xor(v, 2);
    v += __shfl_xor(v, 4);
    v += __shfl_xor(v, 8);
    return v;
}
__device__ inline float sigm(float x) { return 1.0f / (1.0f + __expf(-x)); }
__device__ inline float tanh_fast(float x) {
    float a = fabsf(x);
    float e = __expf(2.0f * a);
    float t = 1.0f - 2.0f / (e + 1.0f);
    return copysignf(t, x);
}
__device__ inline float dot4(f32x4 v) { return v.x*v.x + v.y*v.y + v.z*v.z + v.w*v.w; }
__device__ inline short4v pack4(f32x4 v) {
    short4v p;
    p.x = f2bf(v.x); p.y = f2bf(v.y); p.z = f2bf(v.z); p.w = f2bf(v.w);
    return p;
}

// ---- prep: W_f (256x256) + W_iou (384x256) -> bf16 fragment-linear B ----
__global__ void prep_B(const float* __restrict__ W_f, const float* __restrict__ W_iou,
                       short* __restrict__ Blin) {
    int t = blockIdx.x * 256 + threadIdx.x;
    if (t >= 8 * 40 * 64) return;
    int lane = t & 63;
    int jb = (t >> 6) % 40;
    int kb = (t >> 6) / 40;
    int j = jb * 16 + (lane & 15);
    int k = kb * 32 + ((lane >> 4) << 3);
    const float* src = (j < 256) ? (W_f + (size_t)j * 256 + k)
                                 : (W_iou + (size_t)(j - 256) * 256 + k);
    bf16x8 v;
#pragma unroll
    for (int e = 0; e < 8; ++e) v[e] = f2bf(src[e]);
    *(bf16x8*)(Blin + (size_t)t * 8) = v;
}

// GEMM pass over 32x256 A tile (fragment-linear chunks, XOR-swizzled): NJJ
// col-blocks starting at jbase, 2 M-frags. Fragment index f = kb*128 + kg*32 + row.
template<int NJJ>
__device__ inline void gpass32(const short* __restrict__ A, const short* __restrict__ Blin,
                               int lane, int jbase, f32x4 acc[2][NJJ]) {
    const int la = lane & 15, kg = lane >> 4;
#pragma unroll
    for (int kb = 0; kb < 8; ++kb) {
        bf16x8 af[2];
#pragma unroll
        for (int m = 0; m < 2; ++m) {
            const int f = kb * 128 + kg * 32 + m * 16 + la;
            af[m] = *(const bf16x8*)&A[(f ^ ((f >> 5) & 7)) << 3];
        }
#pragma unroll
        for (int jj = 0; jj < NJJ; ++jj) {
            const bf16x8 b = *(const bf16x8*)(Blin +
                ((size_t)((kb * 40 + jbase + jj) * 64 + lane)) * 8);
            acc[0][jj] = __builtin_amdgcn_mfma_f32_16x16x32_bf16(af[0], b, acc[0][jj], 0, 0, 0);
            acc[1][jj] = __builtin_amdgcn_mfma_f32_16x16x32_bf16(af[1], b, acc[1][jj], 0, 0, 0);
        }
    }
}

// ---- fused: TN=32, wave-local epilogue, all per-node state in regs+shfl ----
// LDS exactly 32768 B. Peak AGPR 16; target total regs <= ~60.
__global__ __launch_bounds__(512, 8) void tree_fused(
    const float* __restrict__ h_src, const float* __restrict__ c_src,
    const float* __restrict__ iou, const int* __restrict__ child_idx,
    const float* __restrict__ b_f, const float* __restrict__ b_iou,
    const float* __restrict__ sc_iou_p, const float* __restrict__ sc_c_p,
    const short* __restrict__ Blin, float* __restrict__ out) {
    __shared__ __align__(16) short U[16384];   // 32768 B total

    const int tid = threadIdx.x;
    const int wave = tid >> 6;
    const int lane = tid & 63;
    const int la = lane & 15, kg = lane >> 4;
    const size_t nb0 = (size_t)blockIdx.x * TN;

    const float sc_iou = sc_iou_p[0];
    const float sc_c = sc_c_p[0];

    // one coalesced load covers all (node, child) of this tile; shfl thereafter
    const int myidx = child_idx[nb0 * 2 + lane];

    // epilogue identity: wave-local — node nd_e = wave + 8*(lane>>4), elems h0..h0+7
    const int rr = lane >> 4;
    const int nd_e = wave + 8 * rr;
    const int h0 = la * 8;

    float hn_keep = 0.f, in_keep = 0.f;   // norms for node wave+8r, held in lane r

    // ---------- phase 1: h gather -> A; h/iou norms (2 nodes at a time) ----------
    {
        const int child = lane >> 5;
        const int seg = lane & 31;
#pragma unroll
        for (int half = 0; half < 2; ++half) {
            f32x4 hv[2], v4[2];
            f32x2 v2[2];
            int cix[2];
#pragma unroll
            for (int q = 0; q < 2; ++q) {
                const int r = half * 2 + q;
                const int nd = wave + 8 * r;
                cix[q] = __shfl(myidx, 2 * nd + child);
                const size_t node = nb0 + nd;
                hv[q] = *(const f32x4*)(h_src + (size_t)cix[q] * 128 + seg * 4);
                v4[q] = *(const f32x4*)(iou + node * 384 + lane * 4);
                v2[q] = *(const f32x2*)(iou + node * 384 + 256 + lane * 2);
            }
#pragma unroll
            for (int q = 0; q < 2; ++q) {
                const int r = half * 2 + q;
                const int nd = wave + 8 * r;
                // kfull = child*128 + seg*4 -> kb = child*4 + (seg>>3), kg = (seg>>1)&3
                const int f = (child * 4 + (seg >> 3)) * 128 + ((seg >> 1) & 3) * 32 + nd;
                const int addr = ((f ^ ((f >> 5) & 7)) << 3) + (seg & 1) * 4;
                short4v a4;
                a4.x = f2bf(hv[q].x); a4.y = f2bf(hv[q].y);
                a4.z = f2bf(hv[q].z); a4.w = f2bf(hv[q].w);
                *(short4v*)&U[addr] = a4;
                float hss = wsum64(dot4(hv[q]));
                float iss = wsum64(dot4(v4[q]) + v2[q].x * v2[q].x + v2[q].y * v2[q].y);
                if (lane == r) { hn_keep = hss; in_keep = iss; }
            }
            __builtin_amdgcn_sched_barrier(0);   // keep half-B loads from hoisting
        }
    }
    __syncthreads();   // B1: A visible

    // ---- c prefetch (my node's slice; flies under GEMM-F), bf16-packed ----
    short4v c0p[2], c1p[2];
    float n2c0;
    {
        const int c0i = __shfl(myidx, 2 * nd_e);
        const int c1i = __shfl(myidx, 2 * nd_e + 1);
        const f32x4 t00 = *(const f32x4*)(c_src + (size_t)c0i * 128 + h0);
        const f32x4 t01 = *(const f32x4*)(c_src + (size_t)c0i * 128 + h0 + 4);
        const f32x4 t10 = *(const f32x4*)(c_src + (size_t)c1i * 128 + h0);
        const f32x4 t11 = *(const f32x4*)(c_src + (size_t)c1i * 128 + h0 + 4);
        n2c0 = dot4(t00) + dot4(t01);
        c0p[0] = pack4(t00); c0p[1] = pack4(t01);
        c1p[0] = pack4(t10); c1p[1] = pack4(t11);
    }

    // ---------- GEMM-F: cols 0..255, b_f folded; spill to F region ----------
    {
        f32x4 accf[2][2];
        const float bf0 = b_f[(wave * 2 + 0) * 16 + la];
        const float bf1 = b_f[(wave * 2 + 1) * 16 + la];
        accf[0][0] = (f32x4){bf0, bf0, bf0, bf0};
        accf[1][0] = accf[0][0];
        accf[0][1] = (f32x4){bf1, bf1, bf1, bf1};
        accf[1][1] = accf[0][1];
        gpass32<2>(U, Blin, lane, wave * 2, accf);
#pragma unroll
        for (int m = 0; m < 2; ++m)
#pragma unroll
            for (int jj = 0; jj < 2; ++jj) {
                const int col = (wave * 2 + jj) * 16 + la;
#pragma unroll
                for (int r = 0; r < 4; ++r) {
                    const int row = m * 16 + kg * 4 + r;
                    U[FBASE + row * 256 + (col ^ SWZ(row))] = f2bf(accf[m][jj][r]);
                }
            }
    }
    __syncthreads();   // B2: F visible; A intact

    // ---------- part 1: forget gates + weighted cell sum (my node) ----------
    float csr[8], s_v;
    {
        const int fsw = SWZ(nd_e);
        const bf16x8 yf0 = *(const bf16x8*)&U[FBASE + nd_e * 256 + (h0 ^ fsw)];
        const bf16x8 yf1 = *(const bf16x8*)&U[FBASE + nd_e * 256 + ((128 + h0) ^ fsw)];
        float c0n2 = wsum16(n2c0);
        float csn2 = 0.f;
#pragma unroll
        for (int e = 0; e < 8; ++e) {
            const float f0 = sigm(bf2f(yf0[e]));   // b_f folded into Y
            const float f1 = sigm(bf2f(yf1[e]));
            const float v = f0 * bf2f(c0p[e >> 2][e & 3]) + f1 * bf2f(c1p[e >> 2][e & 3]);
            csr[e] = v;
            csn2 += v * v;
        }
        csn2 = wsum16(csn2);
        const float rs = sc_c * sqrtf(c0n2) / fmaxf(sqrtf(csn2), EPSN);
#pragma unroll
        for (int e = 0; e < 8; ++e) csr[e] *= rs;
        const float hn = __shfl(hn_keep, rr);
        const float inn = __shfl(in_keep, rr);
        s_v = sc_iou * sqrtf(inn) / fmaxf(sqrtf(hn), EPSN);
    }

    // ---------- GEMM-io: col-blocks 16..31 (i,o); 16 AGPR ----------
    f32x4 accio[2][2];
#pragma unroll
    for (int m = 0; m < 2; ++m)
#pragma unroll
        for (int jj = 0; jj < 2; ++jj) accio[m][jj] = (f32x4){0.f, 0.f, 0.f, 0.f};
    gpass32<2>(U, Blin, lane, 16 + wave * 2, accio);
    __syncthreads();   // B3: part1 F-reads done -> F region free

    // io spill -> F region (local cols: i = 0..127, o = 128..255)
#pragma unroll
    for (int m = 0; m < 2; ++m)
#pragma unroll
        for (int jj = 0; jj < 2; ++jj) {
            const int col = (wave * 2 + jj) * 16 + la;
#pragma unroll
            for (int r = 0; r < 4; ++r) {
                const int row = m * 16 + kg * 4 + r;
                U[FBASE + row * 256 + (col ^ SWZ(row))] = f2bf(accio[m][jj][r]);
            }
        }

    // ---------- GEMM-u: col-block 32+wave (u); 8 AGPR ----------
    f32x4 accu[2][1];
    accu[0][0] = (f32x4){0.f, 0.f, 0.f, 0.f};
    accu[1][0] = accu[0][0];
    gpass32<1>(U, Blin, lane, 32 + wave, accu);
    __syncthreads();   // B4: ALL A reads drained -> A region free

    // u spill -> A region (stride 128 shorts, swizzled), local cols 0..127
#pragma unroll
    for (int m = 0; m < 2; ++m) {
        const int col = wave * 16 + la;
#pragma unroll
        for (int r = 0; r < 4; ++r) {
            const int row = m * 16 + kg * 4 + r;
            U[row * 128 + (col ^ SWZ(row))] = f2bf(accu[m][0][r]);
        }
    }
    __syncthreads();   // B5: io + u visible

    // ---------- part 2: i/o/u gates -> h, c (my node, two 4-elem chunks) ----------
    {
        const int fsw = SWZ(nd_e);
        const size_t node = nb0 + nd_e;
#pragma unroll
        for (int ch = 0; ch < 2; ++ch) {
            const int hc = h0 + ch * 4;
            const short4v yi = *(const short4v*)&U[FBASE + nd_e * 256 + (hc ^ fsw)];
            const short4v yo = *(const short4v*)&U[FBASE + nd_e * 256 + ((128 + hc) ^ fsw)];
            const short4v yu = *(const short4v*)&U[nd_e * 128 + (hc ^ fsw)];
            const f32x4 bi = *(const f32x4*)(b_iou + hc);
            const f32x4 bo = *(const f32x4*)(b_iou + 128 + hc);
            const f32x4 bu = *(const f32x4*)(b_iou + 256 + hc);
            f32x4 outh, outc;
#pragma unroll
            for (int e = 0; e < 4; ++e) {
                const float iv = bf2f(yi[e]) * s_v + ((const float*)&bi)[e];
                const float ov = bf2f(yo[e]) * s_v + ((const float*)&bo)[e];
                const float uv = bf2f(yu[e]) * s_v + ((const float*)&bu)[e];
                const float cval = sigm(iv) * tanh_fast(uv) + csr[ch * 4 + e];
                const float hval = sigm(ov) * tanh_fast(cval);
                ((float*)&outh)[e] = hval;
                ((float*)&outc)[e] = cval;
            }
            *(f32x4*)(out + node * 256 + hc) = outh;
            *(f32x4*)(out + node * 256 + 128 + hc) = outc;
        }
    }
}

extern "C" void kernel_launch(void* const* d_in, const int* in_sizes, int n_in,
                              void* d_out, int out_size, void* d_ws, size_t ws_size,
                              hipStream_t stream) {
    const float* h_src = (const float*)d_in[0];
    const float* c_src = (const float*)d_in[1];
    const float* iou = (const float*)d_in[2];
    const int* cidx = (const int*)d_in[3];
    const float* W_f = (const float*)d_in[4];
    const float* b_f = (const float*)d_in[5];
    const float* W_iou = (const float*)d_in[6];
    const float* b_iou = (const float*)d_in[7];
    const float* s_iou = (const float*)d_in[8];
    const float* s_c = (const float*)d_in[9];
    float* out = (float*)d_out;
    short* Blin = (short*)d_ws;

    const int N = in_sizes[3] / 2;        // 200000
    const int ntiles = N / TN;            // 6250
    hipLaunchKernelGGL(prep_B, dim3(80), dim3(256), 0, stream, W_f, W_iou, Blin);
    hipLaunchKernelGGL(tree_fused, dim3(ntiles), dim3(512), 0, stream,
                       h_src, c_src, iou, cidx, b_f, b_iou, s_iou, s_c, Blin, out);
}

// Round 17
// 313.206 us; speedup vs baseline: 1.5577x; 1.5577x over previous
//
#include <hip/hip_runtime.h>
#include <math.h>

typedef __attribute__((ext_vector_type(4))) float f32x4;
typedef __attribute__((ext_vector_type(2))) float f32x2;
typedef __attribute__((ext_vector_type(8))) short bf16x8;
typedef __attribute__((ext_vector_type(4))) short short4v;

#define EPSN 1e-12f
#define TN 32
#define FBASE 8192        // F region base (shorts); A = [0, 8192)
#define CSRB 16384        // csr region base (shorts); total U = 20480 shorts = 40960 B
#define YS 512            // IOU staging row stride (shorts) over [0, 16384)
#define SWZ(row) ((((row) >> 2) & 3) << 4)

__device__ inline short f2bf(float x) {
    union { float f; unsigned u; } v; v.f = x;
    unsigned r = v.u + 0x7fffu + ((v.u >> 16) & 1u);
    return (short)(r >> 16);
}
__device__ inline float bf2f(short s) {
    union { unsigned u; float f; } v;
    v.u = ((unsigned)(unsigned short)s) << 16;
    return v.f;
}
__device__ inline float wsum64(float v) {
#pragma unroll
    for (int m = 32; m > 0; m >>= 1) v += __shfl_xor(v, m);
    return v;
}
__device__ inline float wsum16(float v) {
    v += __shfl_xor(v, 1);
    v += __shfl_xor(v, 2);
    v += __shfl_xor(v, 4);
    v += __shfl_xor(v, 8);
    return v;
}
__device__ inline float sigm(float x) { return 1.0f / (1.0f + __expf(-x)); }
__device__ inline float tanh_fast(float x) {
    float a = fabsf(x);
    float e = __expf(2.0f * a);
    float t = 1.0f - 2.0f / (e + 1.0f);
    return copysignf(t, x);
}
__device__ inline float dot4(f32x4 v) { return v.x*v.x + v.y*v.y + v.z*v.z + v.w*v.w; }

// ---- prep: W_f (256x256) + W_iou (384x256) -> bf16 fragment-linear B ----
__global__ void prep_B(const float* __restrict__ W_f, const float* __restrict__ W_iou,
                       short* __restrict__ Blin) {
    int t = blockIdx.x * 256 + threadIdx.x;
    if (t >= 8 * 40 * 64) return;
    int lane = t & 63;
    int jb = (t >> 6) % 40;
    int kb = (t >> 6) / 40;
    int j = jb * 16 + (lane & 15);
    int k = kb * 32 + ((lane >> 4) << 3);
    const float* src = (j < 256) ? (W_f + (size_t)j * 256 + k)
                                 : (W_iou + (size_t)(j - 256) * 256 + k);
    bf16x8 v;
#pragma unroll
    for (int e = 0; e < 8; ++e) v[e] = f2bf(src[e]);
    *(bf16x8*)(Blin + (size_t)t * 8) = v;
}

// GEMM pass over 32x256 A tile (fragment-linear chunks, XOR-swizzled): NJJ
// col-blocks starting at jbase, 2 M-frags. Fragment index f = kb*128 + kg*32 + row.
template<int NJJ>
__device__ inline void gpass32(const short* __restrict__ A, const short* __restrict__ Blin,
                               int lane, int jbase, f32x4 acc[2][NJJ]) {
    const int la = lane & 15, kg = lane >> 4;
#pragma unroll
    for (int kb = 0; kb < 8; ++kb) {
        bf16x8 af[2];
#pragma unroll
        for (int m = 0; m < 2; ++m) {
            const int f = kb * 128 + kg * 32 + m * 16 + la;
            af[m] = *(const bf16x8*)&A[(f ^ ((f >> 5) & 7)) << 3];
        }
#pragma unroll
        for (int jj = 0; jj < NJJ; ++jj) {
            const bf16x8 b = *(const bf16x8*)(Blin +
                ((size_t)((kb * 40 + jbase + jj) * 64 + lane)) * 8);
            acc[0][jj] = __builtin_amdgcn_mfma_f32_16x16x32_bf16(af[0], b, acc[0][jj], 0, 0, 0);
            acc[1][jj] = __builtin_amdgcn_mfma_f32_16x16x32_bf16(af[1], b, acc[1][jj], 0, 0, 0);
        }
    }
}

// ---- fused: TN=32, wave-local epilogue, every phase <= 32 arch VGPRs ----
__global__ __launch_bounds__(512, 8) void tree_fused(
    const float* __restrict__ h_src, const float* __restrict__ c_src,
    const float* __restrict__ iou, const int* __restrict__ child_idx,
    const float* __restrict__ b_f, const float* __restrict__ b_iou,
    const float* __restrict__ sc_iou_p, const float* __restrict__ sc_c_p,
    const short* __restrict__ Blin, float* __restrict__ out) {
    __shared__ __align__(16) short U[20480];   // 40960 B exactly

    const int tid = threadIdx.x;
    const int wave = tid >> 6;
    const int lane = tid & 63;
    const int la = lane & 15, kg = lane >> 4;
    const size_t nb0 = (size_t)blockIdx.x * TN;

    const float sc_iou = sc_iou_p[0];
    const float sc_c = sc_c_p[0];

    // one coalesced load covers all (node, child) of this tile; shfl thereafter
    const int myidx = child_idx[nb0 * 2 + lane];

    // wave-local epilogue identity: node nd_e = wave + 8*kg, elems h0..h0+7
    const int nd_e = wave + 8 * kg;
    const int h0 = la * 8;

    float hn_keep = 0.f, in_keep = 0.f;   // norms for node wave+8r live in lane r

    // ---------- phase 1: one node per step (<=10 load regs in flight) ----------
    {
        const int child = lane >> 5;
        const int seg = lane & 31;
#pragma unroll
        for (int r = 0; r < 4; ++r) {
            const int nd = wave + 8 * r;
            const int cix = __shfl(myidx, 2 * nd + child);
            const size_t node = nb0 + nd;
            const f32x4 hv = *(const f32x4*)(h_src + (size_t)cix * 128 + seg * 4);
            const f32x4 v4 = *(const f32x4*)(iou + node * 384 + lane * 4);
            const f32x2 v2 = *(const f32x2*)(iou + node * 384 + 256 + lane * 2);
            // kfull = child*128 + seg*4 -> kb = child*4 + (seg>>3), kgf = (seg>>1)&3
            const int f = (child * 4 + (seg >> 3)) * 128 + ((seg >> 1) & 3) * 32 + nd;
            const int addr = ((f ^ ((f >> 5) & 7)) << 3) + (seg & 1) * 4;
            short4v a4;
            a4.x = f2bf(hv.x); a4.y = f2bf(hv.y); a4.z = f2bf(hv.z); a4.w = f2bf(hv.w);
            *(short4v*)&U[addr] = a4;
            float hss = wsum64(dot4(hv));
            float iss = wsum64(dot4(v4) + v2.x * v2.x + v2.y * v2.y);
            if (lane == r) { hn_keep = hss; in_keep = iss; }
            __builtin_amdgcn_sched_barrier(0);   // cap in-flight regs per step
        }
    }
    __syncthreads();   // B1: A visible

    // ---------- GEMM-F: cols 0..255, b_f folded; 16 AGPR, lean VGPR ----------
    {
        f32x4 accf[2][2];
        const float bf0 = b_f[(wave * 2 + 0) * 16 + la];
        const float bf1 = b_f[(wave * 2 + 1) * 16 + la];
        accf[0][0] = (f32x4){bf0, bf0, bf0, bf0};
        accf[1][0] = accf[0][0];
        accf[0][1] = (f32x4){bf1, bf1, bf1, bf1};
        accf[1][1] = accf[0][1];
        gpass32<2>(U, Blin, lane, wave * 2, accf);
        // F spill: stride 256, XOR swizzle (conflict-free scalar writes)
#pragma unroll
        for (int m = 0; m < 2; ++m)
#pragma unroll
            for (int jj = 0; jj < 2; ++jj) {
                const int col = (wave * 2 + jj) * 16 + la;
#pragma unroll
                for (int r = 0; r < 4; ++r) {
                    const int row = m * 16 + kg * 4 + r;
                    U[FBASE + row * 256 + (col ^ SWZ(row))] = f2bf(accf[m][jj][r]);
                }
            }
    }
    __syncthreads();   // B2: F visible; A intact

    // ---------- part 1: c gather + forget gates; csr -> LDS (bf16) ----------
    float s_v;
    {
        const int c0i = __shfl(myidx, 2 * nd_e);
        const int c1i = __shfl(myidx, 2 * nd_e + 1);
        const int fsw = SWZ(nd_e);
        const bf16x8 yf0 = *(const bf16x8*)&U[FBASE + nd_e * 256 + (h0 ^ fsw)];
        const bf16x8 yf1 = *(const bf16x8*)&U[FBASE + nd_e * 256 + ((128 + h0) ^ fsw)];

        float cs[8];
        float c0n2;
        {
            const f32x4 c00 = *(const f32x4*)(c_src + (size_t)c0i * 128 + h0);
            const f32x4 c01 = *(const f32x4*)(c_src + (size_t)c0i * 128 + h0 + 4);
            c0n2 = dot4(c00) + dot4(c01);
#pragma unroll
            for (int e = 0; e < 4; ++e) {
                cs[e] = sigm(bf2f(yf0[e])) * ((const float*)&c00)[e];
                cs[4 + e] = sigm(bf2f(yf0[4 + e])) * ((const float*)&c01)[e];
            }
        }
        float csn2 = 0.f;
        {
            const f32x4 c10 = *(const f32x4*)(c_src + (size_t)c1i * 128 + h0);
            const f32x4 c11 = *(const f32x4*)(c_src + (size_t)c1i * 128 + h0 + 4);
#pragma unroll
            for (int e = 0; e < 4; ++e) {
                cs[e] += sigm(bf2f(yf1[e])) * ((const float*)&c10)[e];
                cs[4 + e] += sigm(bf2f(yf1[4 + e])) * ((const float*)&c11)[e];
                csn2 += cs[e] * cs[e] + cs[4 + e] * cs[4 + e];
            }
        }
        c0n2 = wsum16(c0n2);
        csn2 = wsum16(csn2);
        const float rs = sc_c * sqrtf(c0n2) / fmaxf(sqrtf(csn2), EPSN);
        bf16x8 cw;
#pragma unroll
        for (int e = 0; e < 8; ++e) cw[e] = f2bf(cs[e] * rs);
        *(bf16x8*)&U[CSRB + nd_e * 128 + h0] = cw;

        const float hn = __shfl(hn_keep, kg);
        const float inn = __shfl(in_keep, kg);
        s_v = sc_iou * sqrtf(inn) / fmaxf(sqrtf(hn), EPSN);
    }

    // ---------- GEMM-IOU: cols 256..639 single pass; 24 AGPR, lean VGPR ----------
    f32x4 accio[2][3];
#pragma unroll
    for (int m = 0; m < 2; ++m)
#pragma unroll
        for (int jj = 0; jj < 3; ++jj) accio[m][jj] = (f32x4){0.f, 0.f, 0.f, 0.f};
    gpass32<3>(U, Blin, lane, 16 + wave * 3, accio);
    __syncthreads();   // B3: all A reads + part1 F reads done; csr written

    // ---------- IOU spill over dead A+F ([0,16384), stride YS, XOR swz) ----------
#pragma unroll
    for (int m = 0; m < 2; ++m)
#pragma unroll
        for (int jj = 0; jj < 3; ++jj) {
            const int col = (wave * 3 + jj) * 16 + la;   // 0..383 = i|o|u
#pragma unroll
            for (int r = 0; r < 4; ++r) {
                const int row = m * 16 + kg * 4 + r;
                U[row * YS + (col ^ SWZ(row))] = f2bf(accio[m][jj][r]);
            }
        }
    __syncthreads();   // B4: IOU staging visible

    // ---------- part 2: i/o/u gates -> h, c (my node, two 4-elem chunks) ----------
    {
        const int fsw = SWZ(nd_e);
        const size_t node = nb0 + nd_e;
        const bf16x8 csrv = *(const bf16x8*)&U[CSRB + nd_e * 128 + h0];
#pragma unroll
        for (int ch = 0; ch < 2; ++ch) {
            const int hc = h0 + ch * 4;
            const short4v yi = *(const short4v*)&U[nd_e * YS + (hc ^ fsw)];
            const short4v yo = *(const short4v*)&U[nd_e * YS + ((128 + hc) ^ fsw)];
            const short4v yu = *(const short4v*)&U[nd_e * YS + ((256 + hc) ^ fsw)];
            const f32x4 bi = *(const f32x4*)(b_iou + hc);
            const f32x4 bo = *(const f32x4*)(b_iou + 128 + hc);
            const f32x4 bu = *(const f32x4*)(b_iou + 256 + hc);
            f32x4 outh, outc;
#pragma unroll
            for (int e = 0; e < 4; ++e) {
                const float iv = bf2f(yi[e]) * s_v + ((const float*)&bi)[e];
                const float ov = bf2f(yo[e]) * s_v + ((const float*)&bo)[e];
                const float uv = bf2f(yu[e]) * s_v + ((const float*)&bu)[e];
                const float cval = sigm(iv) * tanh_fast(uv) + bf2f(csrv[ch * 4 + e]);
                const float hval = sigm(ov) * tanh_fast(cval);
                ((float*)&outh)[e] = hval;
                ((float*)&outc)[e] = cval;
            }
            *(f32x4*)(out + node * 256 + hc) = outh;
            *(f32x4*)(out + node * 256 + 128 + hc) = outc;
        }
    }
}

extern "C" void kernel_launch(void* const* d_in, const int* in_sizes, int n_in,
                              void* d_out, int out_size, void* d_ws, size_t ws_size,
                              hipStream_t stream) {
    const float* h_src = (const float*)d_in[0];
    const float* c_src = (const float*)d_in[1];
    const float* iou = (const float*)d_in[2];
    const int* cidx = (const int*)d_in[3];
    const float* W_f = (const float*)d_in[4];
    const float* b_f = (const float*)d_in[5];
    const float* W_iou = (const float*)d_in[6];
    const float* b_iou = (const float*)d_in[7];
    const float* s_iou = (const float*)d_in[8];
    const float* s_c = (const float*)d_in[9];
    float* out = (float*)d_out;
    short* Blin = (short*)d_ws;

    const int N = in_sizes[3] / 2;        // 200000
    const int ntiles = N / TN;            // 6250
    hipLaunchKernelGGL(prep_B, dim3(80), dim3(256), 0, stream, W_f, W_iou, Blin);
    hipLaunchKernelGGL(tree_fused, dim3(ntiles), dim3(512), 0, stream,
                       h_src, c_src, iou, cidx, b_f, b_iou, s_iou, s_c, Blin, out);
}